// Round 7
// baseline (247.873 us; speedup 1.0000x reference)
//
#include <hip/hip_runtime.h>
#include <hip/hip_bf16.h>
#include <math.h>

// Problem constants
#define LSEQ   4096
#define DIM    768
#define DINNER 1536
#define DSTATE 16
#define NCOLS  4640          // 3*DINNER + 2*DSTATE
#define NCH    128           // scan chunks
#define CLEN   32            // steps per chunk
#define NPAD   4736          // W_in rows padded to 37*128

typedef _Float16 f16;
typedef __attribute__((ext_vector_type(8))) _Float16 f16x8;
typedef __attribute__((ext_vector_type(4))) float f32x4;

// async global(16B/lane) -> LDS staging
__device__ __forceinline__ void gld_lds16(void* lds_dst, const void* gsrc) {
    __builtin_amdgcn_global_load_lds(
        (__attribute__((address_space(1))) void*)(gsrc),
        (__attribute__((address_space(3))) void*)(lds_dst), 16, 0, 0);
}

// ---------------------------------------------------------------------------
// fp16 MFMA GEMM, BK=32, 2-stage LDS pipeline:
//   C = A[M,K](f16) * B[N,K]^T(f16), fp32 accumulate.
// LDS: 2 stages x (BM+BN) rows x 32 f16. Two 64B rows share a 128B line;
// 16B slots XOR-swizzled by line index: staging lane L (l=L>>3,s=L&7) fetches
// global (row 2l+(b8>>2), kblk b8&3) with b8 = s^l; read side inverts with
// slot = (((R&1)<<2)|q) ^ (line&7). Conflict-free (2-way max).
// Pipeline: iter s stages k-tile s+1, computes tile s, ONE barrier per iter —
// the pre-barrier vmcnt(0) drain overlaps the whole MFMA phase.
// ZMODE (GEMM1): cols [0,1536)->f16 Xb, [1536,3072)->f16 Zb,
//   [3072,3104)->f32 BC (B|C compact, width 32), [3104,4640)->f16 Db (delta).
// XCD swizzle: idx=(b&7)*P+(b>>3); COLM picks which dim varies fastest.
// ---------------------------------------------------------------------------
template<int BM, int BN, int WM, int WN, int NTB, bool COLM, bool ZMODE>
__global__ __launch_bounds__(256) void gemm_f16(const f16* __restrict__ A,
                                                const f16* __restrict__ B,
                                                float* __restrict__ C,
                                                f16* __restrict__ Xb,
                                                f16* __restrict__ Zb,
                                                float* __restrict__ BC,
                                                f16* __restrict__ Db,
                                                int M, int N, int K, int ldc) {
    constexpr int MI  = WM / 16;
    constexpr int NI  = WN / 16;
    constexpr int NWN = BN / WN;
    constexpr int RT  = BM + BN;          // rows per stage
    constexpr int NS  = RT / 16;          // 1KB staging instrs per stage
    constexpr int SSZ = RT * 32;          // f16 elems per stage

    __shared__ __align__(16) f16 S[2 * SSZ];

    const int P   = gridDim.x >> 3;
    const int idx = (blockIdx.x & 7) * P + (blockIdx.x >> 3);
    const int m0  = (COLM ? (idx % NTB) : (idx / NTB)) * BM;
    const int n0  = (COLM ? (idx / NTB) : (idx % NTB)) * BN;

    const int tid  = threadIdx.x;
    const int w    = tid >> 6;
    const int lane = tid & 63;
    const int wr   = w / NWN;
    const int wc   = w % NWN;
    const int m    = lane & 15;           // fragment row(A)/col(B)
    const int q    = lane >> 4;           // quad -> k-group q*8
    // staging decode for this lane
    const int ell  = lane >> 3;           // line within 8-line group
    const int b8   = (lane & 7) ^ ell;    // swizzled slot -> global block id
    const int rofs = 2 * ell + (b8 >> 2); // row within 16-row group
    const int kofs = (b8 & 3) * 8;        // k element offset

    f32x4 acc[MI][NI];
#pragma unroll
    for (int i = 0; i < MI; i++)
#pragma unroll
        for (int j = 0; j < NI; j++) acc[i][j] = (f32x4){0.f, 0.f, 0.f, 0.f};

    auto stage = [&](int st, int k0) {
#pragma unroll
        for (int t = w; t < NS; t += 4) {
            const int rl = t * 16 + rofs;
            const f16* g = (t * 16 < BM)
                ? A + (size_t)(m0 + rl) * K + k0 + kofs
                : B + (size_t)(n0 + rl - BM) * K + k0 + kofs;
            gld_lds16(S + st * SSZ + t * 512, g);
        }
    };

    const int NK = K / 32;
    stage(0, 0);
    __syncthreads();

    for (int s = 0; s < NK; s++) {
        if (s + 1 < NK) stage((s + 1) & 1, (s + 1) * 32);
        const f16* sb = S + (s & 1) * SSZ;
        f16x8 af[MI], bh[NI];
#pragma unroll
        for (int i = 0; i < MI; i++) {
            const int R = wr * WM + i * 16 + m;
            const int line = R >> 1;
            const int slot = ((((R & 1) << 2) | q) ^ (line & 7));
            af[i] = *(const f16x8*)&sb[line * 64 + slot * 8];
        }
#pragma unroll
        for (int j = 0; j < NI; j++) {
            const int R = BM + wc * WN + j * 16 + m;
            const int line = R >> 1;
            const int slot = ((((R & 1) << 2) | q) ^ (line & 7));
            bh[j] = *(const f16x8*)&sb[line * 64 + slot * 8];
        }
#pragma unroll
        for (int i = 0; i < MI; i++)
#pragma unroll
            for (int j = 0; j < NI; j++)
                acc[i][j] = __builtin_amdgcn_mfma_f32_16x16x32_f16(
                    af[i], bh[j], acc[i][j], 0, 0, 0);
        __syncthreads();
    }

    // epilogue: C/D layout col=lane&15, row=q*4+reg
    if (ZMODE && n0 < DINNER) {            // x_inner cols -> f16 Xb
#pragma unroll
        for (int i = 0; i < MI; i++)
#pragma unroll
            for (int j = 0; j < NI; j++) {
                const int col  = n0 + wc * WN + j * 16 + m;
                const int rowb = m0 + wr * WM + i * 16 + q * 4;
#pragma unroll
                for (int r = 0; r < 4; r++)
                    Xb[(size_t)(rowb + r) * DINNER + col] = (f16)acc[i][j][r];
            }
        return;
    }
    if (ZMODE && n0 < 2 * DINNER) {        // z cols -> f16 Zb
#pragma unroll
        for (int i = 0; i < MI; i++)
#pragma unroll
            for (int j = 0; j < NI; j++) {
                const int col  = n0 - DINNER + wc * WN + j * 16 + m;
                const int rowb = m0 + wr * WM + i * 16 + q * 4;
#pragma unroll
                for (int r = 0; r < 4; r++)
                    Zb[(size_t)(rowb + r) * DINNER + col] = (f16)acc[i][j][r];
            }
        return;
    }
    if (ZMODE) {                           // B|C -> f32 BC ; delta -> f16 Db
#pragma unroll
        for (int i = 0; i < MI; i++)
#pragma unroll
            for (int j = 0; j < NI; j++) {
                const int col  = n0 + wc * WN + j * 16 + m;
                const int rowb = m0 + wr * WM + i * 16 + q * 4;
                if (col < 3104) {
#pragma unroll
                    for (int r = 0; r < 4; r++)
                        BC[(size_t)(rowb + r) * 32 + (col - 3072)] = acc[i][j][r];
                } else if (col < NCOLS) {
#pragma unroll
                    for (int r = 0; r < 4; r++)
                        Db[(size_t)(rowb + r) * DINNER + (col - 3104)] = (f16)acc[i][j][r];
                }
            }
        return;
    }
#pragma unroll
    for (int i = 0; i < MI; i++)
#pragma unroll
        for (int j = 0; j < NI; j++) {
            const int col  = n0 + wc * WN + j * 16 + m;
            if (col >= N) continue;
            const int rowb = m0 + wr * WM + i * 16 + q * 4;
#pragma unroll
            for (int r = 0; r < 4; r++)
                C[(size_t)(rowb + r) * ldc + col] = acc[i][j][r];
        }
}

// ---------------------------------------------------------------------------
// merged conversions: Ax (f16 x), Bw (f16 W_in, zero-padded), Bo (f16 W_out)
// ---------------------------------------------------------------------------
#define E0 (LSEQ * DIM)            // 3,145,728
#define E1 (E0 + NPAD * DIM)       // + 3,637,248
#define E2 (E1 + DIM * DINNER)     // + 1,179,648

__global__ __launch_bounds__(256) void cvt_all(const float* __restrict__ x,
                                               const float* __restrict__ Wi,
                                               const float* __restrict__ Wo,
                                               f16* __restrict__ Ax,
                                               f16* __restrict__ Bw,
                                               f16* __restrict__ Bo) {
    int i = (blockIdx.x * 256 + threadIdx.x) * 4;
    if (i < E0) {
        float4 v = *(const float4*)(x + i);
        Ax[i] = (f16)v.x; Ax[i+1] = (f16)v.y; Ax[i+2] = (f16)v.z; Ax[i+3] = (f16)v.w;
    } else if (i < E1) {
        int e = i - E0;
        int n = e / DIM;
        if (n < NCOLS) {
            float4 v = *(const float4*)(Wi + e);
            Bw[e] = (f16)v.x; Bw[e+1] = (f16)v.y; Bw[e+2] = (f16)v.z; Bw[e+3] = (f16)v.w;
        } else {
            Bw[e] = (f16)0.f; Bw[e+1] = (f16)0.f; Bw[e+2] = (f16)0.f; Bw[e+3] = (f16)0.f;
        }
    } else if (i < E2) {
        int e = i - E1;
        float4 v = *(const float4*)(Wo + e);
        Bo[e] = (f16)v.x; Bo[e+1] = (f16)v.y; Bo[e+2] = (f16)v.z; Bo[e+3] = (f16)v.w;
    }
}

// ---------------------------------------------------------------------------
// scan phase 1: conv+silu+softplus fused; local scan h=0 -> h_end; aprod.
// x from f16 Xb; delta from f16 Db; B from f32 BC (width 32: B|C).
// ---------------------------------------------------------------------------
__global__ __launch_bounds__(256) void scan1_kernel(const float* __restrict__ BC,
                                                    const f16* __restrict__ Xb,
                                                    const f16* __restrict__ Db,
                                                    const float* __restrict__ Wc,
                                                    const float* __restrict__ A_log,
                                                    float* __restrict__ aprod,
                                                    float* __restrict__ hend) {
    __shared__ float Bs[CLEN * DSTATE];
    const int d  = blockIdx.x * 256 + threadIdx.x;
    const int c  = blockIdx.y;
    const int l0 = c * CLEN;
    for (int i = threadIdx.x; i < CLEN * DSTATE; i += 256)
        Bs[i] = BC[(size_t)(l0 + (i >> 4)) * 32 + (i & 15)];
    float Areg[DSTATE];
#pragma unroll
    for (int n = 0; n < DSTATE; n++) Areg[n] = -__expf(A_log[d * DSTATE + n]);
    const float w0 = Wc[d * 3 + 0], w1 = Wc[d * 3 + 1], w2 = Wc[d * 3 + 2];
    float xm = (l0 > 0) ? (float)Xb[(size_t)(l0 - 1) * DINNER + d] : 0.f;
    float x0 = (float)Xb[(size_t)l0 * DINNER + d];
    float ld_xp   = (float)Xb[(size_t)(l0 + 1) * DINNER + d];
    float ld_draw = (float)Db[(size_t)l0 * DINNER + d];
    __syncthreads();

    float h[DSTATE];
#pragma unroll
    for (int n = 0; n < DSTATE; n++) h[n] = 0.f;
    float S = 0.f;

    for (int t = 0; t < CLEN; t++) {
        const int l = l0 + t;
        float xp = ld_xp, draw = ld_draw;
        if (t + 1 < CLEN) {
            ld_xp   = (l + 2 < LSEQ) ? (float)Xb[(size_t)(l + 2) * DINNER + d] : 0.f;
            ld_draw = (float)Db[(size_t)(l + 1) * DINNER + d];
        }
        float v  = xm * w0 + x0 * w1 + xp * w2;
        float xcv = __fdividef(v, 1.f + __expf(-v));
        float dtv = (draw > 20.f) ? draw : __logf(1.f + __expf(draw));
        float u = dtv * xcv;
        S += dtv;
#pragma unroll
        for (int n = 0; n < DSTATE; n++) {
            float e = __expf(dtv * Areg[n]);
            h[n] = e * h[n] + u * Bs[t * DSTATE + n];
        }
        xm = x0; x0 = xp;
    }
#pragma unroll
    for (int n = 0; n < DSTATE; n++) {
        size_t idx = ((size_t)c * DSTATE + n) * DINNER + d;
        aprod[idx] = __expf(S * Areg[n]);
        hend[idx]  = h[n];
    }
}

// ---------------------------------------------------------------------------
// scan phase 2: sequential over NCH chunk summaries, pipelined loads
// ---------------------------------------------------------------------------
__global__ __launch_bounds__(256) void scan2_kernel(const float* __restrict__ aprod,
                                                    const float* __restrict__ hend,
                                                    float* __restrict__ hinit) {
    const int g = blockIdx.x * 256 + threadIdx.x;
    const size_t S = (size_t)DSTATE * DINNER;
    size_t idx = g;
    float a = aprod[idx], e = hend[idx];
    float h = 0.f;
#pragma unroll 4
    for (int c = 0; c < NCH; c++) {
        float ac = a, ec = e;
        if (c + 1 < NCH) { a = aprod[idx + S]; e = hend[idx + S]; }
        hinit[idx] = h;
        h = ac * h + ec;
        idx += S;
    }
}

// ---------------------------------------------------------------------------
// scan phase 3: replay from h_init; z-gate from f16 Zb; emit f16 Ay
// ---------------------------------------------------------------------------
__global__ __launch_bounds__(256) void scan3_kernel(const float* __restrict__ BC,
                                                    const f16* __restrict__ Xb,
                                                    const f16* __restrict__ Db,
                                                    const f16* __restrict__ Zb,
                                                    const float* __restrict__ Wc,
                                                    const float* __restrict__ A_log,
                                                    const float* __restrict__ hinit,
                                                    const float* __restrict__ Dp,
                                                    f16* __restrict__ Ay) {
    __shared__ float Bs[CLEN * DSTATE];
    __shared__ float Cs[CLEN * DSTATE];
    const int d  = blockIdx.x * 256 + threadIdx.x;
    const int c  = blockIdx.y;
    const int l0 = c * CLEN;
    for (int i = threadIdx.x; i < CLEN * DSTATE; i += 256) {
        size_t roff = (size_t)(l0 + (i >> 4)) * 32;
        Bs[i] = BC[roff + (i & 15)];
        Cs[i] = BC[roff + 16 + (i & 15)];
    }
    float Areg[DSTATE];
#pragma unroll
    for (int n = 0; n < DSTATE; n++) Areg[n] = -__expf(A_log[d * DSTATE + n]);
    float h[DSTATE];
#pragma unroll
    for (int n = 0; n < DSTATE; n++)
        h[n] = hinit[((size_t)c * DSTATE + n) * DINNER + d];
    const float Dv = Dp[d];
    const float w0 = Wc[d * 3 + 0], w1 = Wc[d * 3 + 1], w2 = Wc[d * 3 + 2];
    float xm = (l0 > 0) ? (float)Xb[(size_t)(l0 - 1) * DINNER + d] : 0.f;
    float x0 = (float)Xb[(size_t)l0 * DINNER + d];
    float ld_xp   = (float)Xb[(size_t)(l0 + 1) * DINNER + d];
    float ld_draw = (float)Db[(size_t)l0 * DINNER + d];
    float ld_z    = (float)Zb[(size_t)l0 * DINNER + d];
    __syncthreads();

    for (int t = 0; t < CLEN; t++) {
        const int l = l0 + t;
        float xp = ld_xp, draw = ld_draw, zv = ld_z;
        if (t + 1 < CLEN) {
            ld_xp   = (l + 2 < LSEQ) ? (float)Xb[(size_t)(l + 2) * DINNER + d] : 0.f;
            ld_draw = (float)Db[(size_t)(l + 1) * DINNER + d];
            ld_z    = (float)Zb[(size_t)(l + 1) * DINNER + d];
        }
        float v  = xm * w0 + x0 * w1 + xp * w2;
        float xcv = __fdividef(v, 1.f + __expf(-v));
        float dtv = (draw > 20.f) ? draw : __logf(1.f + __expf(draw));
        float u = dtv * xcv;
        float y = 0.f;
#pragma unroll
        for (int n = 0; n < DSTATE; n++) {
            float e = __expf(dtv * Areg[n]);
            h[n] = e * h[n] + u * Bs[t * DSTATE + n];
            y += h[n] * Cs[t * DSTATE + n];
        }
        float sz = __fdividef(zv, 1.f + __expf(-zv));
        Ay[(size_t)l * DINNER + d] = (f16)((y + xcv * Dv) * sz);
        xm = x0; x0 = xp;
    }
}

// ---------------------------------------------------------------------------
extern "C" void kernel_launch(void* const* d_in, const int* in_sizes, int n_in,
                              void* d_out, int out_size, void* d_ws, size_t ws_size,
                              hipStream_t stream) {
    const float* x     = (const float*)d_in[0];
    const float* W_in  = (const float*)d_in[1];
    const float* W_conv= (const float*)d_in[2];
    const float* W_out = (const float*)d_in[3];
    const float* A_log = (const float*)d_in[4];
    const float* Dp    = (const float*)d_in[5];
    float* out = (float*)d_out;

    // workspace carve-up (~105 MB)
    float* ws  = (float*)d_ws;
    float* BC  = ws;                                  // 4096*32 f32
    float* ap  = BC + (size_t)LSEQ * 32;              // 3,145,728
    float* he  = ap + (size_t)NCH * DSTATE * DINNER;  // 3,145,728
    float* hi  = he + (size_t)NCH * DSTATE * DINNER;  // 3,145,728
    f16* Ax = (f16*)(hi + (size_t)NCH * DSTATE * DINNER); // 4096*768
    f16* Ay = Ax + (size_t)LSEQ * DIM;                // 4096*1536
    f16* Bw = Ay + (size_t)LSEQ * DINNER;             // 4736*768
    f16* Bo = Bw + (size_t)NPAD * DIM;                // 768*1536
    f16* Zb = Bo + (size_t)DIM * DINNER;              // 4096*1536
    f16* Xb = Zb + (size_t)LSEQ * DINNER;             // 4096*1536
    f16* Db = Xb + (size_t)LSEQ * DINNER;             // 4096*1536

    // 0) conversions (one kernel)
    cvt_all<<<E2 / 1024, 256, 0, stream>>>(x, W_in, W_out, Ax, Bw, Bo);

    // 1) xz = x @ W_in^T : pipelined BK=32; x_inner->Xb, z->Zb, B/C->BC, delta->Db
    //    32 M-tiles x 37 N-tiles = 1184 blocks, col-major XCD slab (B-locality)
    gemm_f16<128, 128, 64, 64, 32, true, true><<<1184, 256, 0, stream>>>(
        Ax, Bw, nullptr, Xb, Zb, BC, Db, LSEQ, NCOLS, DIM, 0);

    // 2) chunked scan
    scan1_kernel<<<dim3(DINNER / 256, NCH), 256, 0, stream>>>(
        BC, Xb, Db, W_conv, A_log, ap, he);
    scan2_kernel<<<(DINNER * DSTATE) / 256, 256, 0, stream>>>(ap, he, hi);
    scan3_kernel<<<dim3(DINNER / 256, NCH), 256, 0, stream>>>(
        BC, Xb, Db, Zb, W_conv, A_log, hi, Dp, Ay);

    // 3) out = yf @ W_out^T : pipelined BK=32, 64 M-tiles x 12 N-tiles = 768 blocks
    gemm_f16<64, 64, 32, 32, 12, false, false><<<768, 256, 0, stream>>>(
        Ay, Bo, out, nullptr, nullptr, nullptr, nullptr, LSEQ, DIM, DINNER, DIM);
}